// Round 7
// baseline (214.101 us; speedup 1.0000x reference)
//
#include <hip/hip_runtime.h>
#include <hip/hip_fp16.h>

// DSA varlen sparse attention, MI355X — round 17: occupancy reshape.
// R16 post-mortem: PASSED (fence fixed the NaN -> LDS mixed-type reorder
// confirmed), but dsa_main=61us with MfmaUtil 10.5 / VALUBusy 28 / Occ 20%:
// 54KB LDS + 512thr -> 1 block/CU, so 3 barriers x 16 iters stall the whole
// CU (~9100 cyc/iter vs ~600 cyc of work). R17: 128-token tiles, 256 thr
// (4 waves), 36KB LDS -> 4 blocks/CU; grid 512 = 4 docs x 8 qtiles x 16
// heads. Per-wave math identical to R16 (verified absmax 0.015625); only
// staging re-indexed. Inter-block TLP hides barrier + L2 latency.
//   sel[t][lr] = scatter-add of selector scores (== reference's clamped-dup
//   handling);  P = exp2(QK^T * 0.125*log2e) .* sel ;  O = P V / rowsum(P).

#define T_TOK 4096
#define NH    16
#define HD    64
#define KSEL  64

typedef _Float16 f16;
typedef _Float16 f16x8 __attribute__((ext_vector_type(8)));
typedef float    f32x4 __attribute__((ext_vector_type(4)));

#define LSTR 72              // LDS row stride in halfs (= 9 uint4, 144B)

static __device__ __forceinline__ float exp2_hw(float x) {
    float r; asm("v_exp_f32 %0, %1" : "=v"(r) : "v"(x)); return r;
}
// DPP adds within 16-lane rows: xor1, xor2, half_mirror, mirror (R10-proven)
template<int CTRL>
static __device__ __forceinline__ float dpp_addf(float x) {
    const int s = __builtin_amdgcn_update_dpp(
        0, __builtin_bit_cast(int, x), CTRL, 0xF, 0xF, true);
    return x + __builtin_bit_cast(float, s);
}
static __device__ __forceinline__ uint4 pack8(float4 a, float4 b) {
    uint4 u;
    u.x = __builtin_bit_cast(unsigned, __floats2half2_rn(a.x, a.y));
    u.y = __builtin_bit_cast(unsigned, __floats2half2_rn(a.z, a.w));
    u.z = __builtin_bit_cast(unsigned, __floats2half2_rn(b.x, b.y));
    u.w = __builtin_bit_cast(unsigned, __floats2half2_rn(b.z, b.w));
    return u;
}

// ---- V -> fp16 TRANSPOSED head-major: vT[h][d][g] (LDS transpose) ----
__global__ __launch_bounds__(256) void vt_build(
    const float* __restrict__ vM, uint4* __restrict__ vT)
{
    __shared__ __align__(16) f16 T[64 * 136];       // [d][128 g], padded
    const int h  = blockIdx.x >> 5;
    const int gb = blockIdx.x & 31;                 // 128-token block
    const int tid = threadIdx.x;
    const int gl = tid >> 1, hf = tid & 1;
    const float* src = vM + (((gb * 128 + gl) * NH + h) << 6) + 32 * hf;
    #pragma unroll
    for (int jj = 0; jj < 8; ++jj) {
        const float4 f = *(const float4*)(src + 4 * jj);
        const int d0 = 32 * hf + 4 * jj;
        T[(d0 + 0) * 136 + gl] = (f16)f.x;
        T[(d0 + 1) * 136 + gl] = (f16)f.y;
        T[(d0 + 2) * 136 + gl] = (f16)f.z;
        T[(d0 + 3) * 136 + gl] = (f16)f.w;
    }
    __syncthreads();
    #pragma unroll
    for (int k = 0; k < 4; ++k) {
        const int idx = tid + 256 * k;              // 1024 u4
        const int d = idx >> 4, c = idx & 15;
        vT[((h * HD + d) << 9) + (gb << 4) + c] = *(const uint4*)&T[d * 136 + 8 * c];
    }
}

// ---- sel[t][lr] scatter-add build: one wave per token ----
__global__ __launch_bounds__(256) void sel_build(
    const int* __restrict__ tidx, const float* __restrict__ tsc,
    const int* __restrict__ cu, uint4* __restrict__ selH, int num_docs)
{
    __shared__ float row[4][1024];
    const int wv = threadIdx.x >> 6, l = threadIdx.x & 63;
    const int t = blockIdx.x * 4 + wv;
    #pragma unroll
    for (int k = 0; k < 4; ++k)
        *(float4*)&row[wv][l * 16 + 4 * k] = make_float4(0.f, 0.f, 0.f, 0.f);
    __syncthreads();
    int seg = 0;
    for (int i = 1; i < num_docs; ++i) if (t >= cu[i]) seg = i;
    const int start = cu[seg];
    const int len   = cu[seg + 1] - start;
    int loc = tidx[t * KSEL + l] - start;
    loc = loc < 0 ? 0 : (loc > len - 1 ? len - 1 : loc);
    atomicAdd(&row[wv][loc], tsc[t * KSEL + l]);
    __syncthreads();
    #pragma unroll
    for (int k = 0; k < 2; ++k) {
        const float* rp = &row[wv][l * 16 + 8 * k];
        const float4 a = *(const float4*)rp;
        const float4 b = *(const float4*)(rp + 4);
        selH[(t << 7) + l * 2 + k] = pack8(a, b);
    }
}

// -------- main: block = (doc, qtile of 128 tok, head); 4 waves --------
__global__ __launch_bounds__(256, 4) void dsa_main(
    const float* __restrict__ qM,
    const float* __restrict__ kM,
    const uint4* __restrict__ vT,
    const uint4* __restrict__ selH,
    const int*   __restrict__ cu,
    float*       __restrict__ out)
{
    __shared__ __align__(16) f16 KtS[64 * LSTR];    //  9 KB [kv][dim]
    __shared__ __align__(16) f16 VtS[64 * LSTR];    //  9 KB [dim][kv]
    __shared__ __align__(16) f16 PS[128 * LSTR];    // 18 KB [tok][kv] sel->P

    const int tid = threadIdx.x;
    const int w   = tid >> 6;          // 0..3
    const int l   = tid & 63;
    const int g4  = l >> 4;
    const int c16 = l & 15;

    const int b    = blockIdx.x;                    // 512 blocks
    const int head = ((b & 7) << 1) | ((b >> 3) & 1);   // head&7 -> XCD pin
    const int doc  = (b >> 4) & 3;
    const int qt   = b >> 6;                        // 0..7

    const int start = cu[doc];
    const int len   = cu[doc + 1] - start;
    const int t0    = start + qt * 128;

    // Q A-fragments in registers, pre-scaled by D^-0.5 * log2(e)
    const float qs = 0.125f * 1.44269504088896f;
    f16x8 qf[2][2];
    #pragma unroll
    for (int m = 0; m < 2; ++m)
    #pragma unroll
    for (int ks = 0; ks < 2; ++ks) {
        const float* qp = qM + (((t0 + 32 * w + 16 * m + c16) * NH + head) << 6)
                        + 32 * ks + 8 * g4;
        float4 a = *(const float4*)qp;
        float4 c = *(const float4*)(qp + 4);
        a.x *= qs; a.y *= qs; a.z *= qs; a.w *= qs;
        c.x *= qs; c.y *= qs; c.z *= qs; c.w *= qs;
        qf[m][ks] = __builtin_bit_cast(f16x8, pack8(a, c));
    }

    f32x4 O[2][4];
    float psum[2][4];
    #pragma unroll
    for (int m = 0; m < 2; ++m)
    #pragma unroll
    for (int sd = 0; sd < 4; ++sd) {
        O[m][sd] = (f32x4){0.f, 0.f, 0.f, 0.f};
        psum[m][sd] = 0.f;
    }

    const int NT = (len + 63) >> 6;
    const int r8 = tid >> 3, c8 = tid & 7;          // r8 0..31

    uint4 kq0, kq1, vq0, vq1, sq0, sq1, sq2, sq3;
#define LOADSTAGE(IT) {                                                      \
        const int grow_ = start + (IT) * 64;                                 \
        const float* kp0_ = kM + (((grow_ + r8     ) * NH + head) << 6) + 8 * c8; \
        const float* kp1_ = kM + (((grow_ + r8 + 32) * NH + head) << 6) + 8 * c8; \
        kq0 = pack8(*(const float4*)kp0_, *(const float4*)(kp0_ + 4));       \
        kq1 = pack8(*(const float4*)kp1_, *(const float4*)(kp1_ + 4));       \
        vq0 = vT[((head * HD + r8     ) << 9) + (grow_ >> 3) + c8];          \
        vq1 = vT[((head * HD + r8 + 32) << 9) + (grow_ >> 3) + c8];          \
        sq0 = selH[((t0 + r8     ) << 7) + ((IT) << 3) + c8];                \
        sq1 = selH[((t0 + r8 + 32) << 7) + ((IT) << 3) + c8];                \
        sq2 = selH[((t0 + r8 + 64) << 7) + ((IT) << 3) + c8];                \
        sq3 = selH[((t0 + r8 + 96) << 7) + ((IT) << 3) + c8];                \
    }
#define WRITESTAGE() {                                                       \
        ((uint4*)KtS)[(r8     ) * 9 + c8] = kq0;                             \
        ((uint4*)KtS)[(r8 + 32) * 9 + c8] = kq1;                             \
        ((uint4*)VtS)[(r8     ) * 9 + c8] = vq0;                             \
        ((uint4*)VtS)[(r8 + 32) * 9 + c8] = vq1;                             \
        ((uint4*)PS)[(r8     ) * 9 + c8] = sq0;                              \
        ((uint4*)PS)[(r8 + 32) * 9 + c8] = sq1;                              \
        ((uint4*)PS)[(r8 + 64) * 9 + c8] = sq2;                              \
        ((uint4*)PS)[(r8 + 96) * 9 + c8] = sq3;                              \
    }

    LOADSTAGE(0);
    WRITESTAGE();
    __syncthreads();

    for (int it = 0; it < NT; ++it) {
        const bool more = (it + 1 < NT);
        if (more) LOADSTAGE(it + 1);        // prefetch next tile into regs

        // ---- S = Q K^T for this wave's 32 tokens x 64 kv ----
        f32x4 S[2][4];
        #pragma unroll
        for (int m = 0; m < 2; ++m)
        #pragma unroll
        for (int s = 0; s < 4; ++s)
            S[m][s] = (f32x4){0.f, 0.f, 0.f, 0.f};
        #pragma unroll
        for (int ks = 0; ks < 2; ++ks) {
            f16x8 kf[4];
            #pragma unroll
            for (int s = 0; s < 4; ++s)
                kf[s] = __builtin_bit_cast(f16x8,
                    ((const uint4*)KtS)[(16 * s + c16) * 9 + 4 * ks + g4]);
            #pragma unroll
            for (int m = 0; m < 2; ++m)
            #pragma unroll
            for (int s = 0; s < 4; ++s)
                S[m][s] = __builtin_amdgcn_mfma_f32_16x16x32_f16(
                    qf[m][ks], kf[s], S[m][s], 0, 0, 0);
        }

        // ---- P = exp2(min(S,30)) * sel, in place over the sel tile ----
        #pragma unroll
        for (int m = 0; m < 2; ++m)
        #pragma unroll
        for (int s = 0; s < 4; ++s)
        #pragma unroll
        for (int r = 0; r < 4; ++r) {
            const int tok  = 32 * w + 16 * m + 4 * g4 + r;
            const int hidx = tok * LSTR + 16 * s + c16;
            const float sel = (float)PS[hidx];
            const float p = fminf(exp2_hw(fminf(S[m][s][r], 30.f)) * sel,
                                  60000.f);
            psum[m][r] += p;
            PS[hidx] = (f16)p;
        }

        // fence: f16 stores (above) vs uint4 loads (below) are mixed-TBAA;
        // a real barrier orders them regardless of aliasing assumptions.
        __syncthreads();

        // ---- O += P V  (A = P rows, B = Vt rows) ----
        #pragma unroll
        for (int ks = 0; ks < 2; ++ks) {
            f16x8 af[2];
            #pragma unroll
            for (int m = 0; m < 2; ++m)
                af[m] = __builtin_bit_cast(f16x8,
                    ((const uint4*)PS)[(32 * w + 16 * m + c16) * 9 + 4 * ks + g4]);
            #pragma unroll
            for (int sd = 0; sd < 4; ++sd) {
                const f16x8 vf = __builtin_bit_cast(f16x8,
                    ((const uint4*)VtS)[(16 * sd + c16) * 9 + 4 * ks + g4]);
                #pragma unroll
                for (int m = 0; m < 2; ++m)
                    O[m][sd] = __builtin_amdgcn_mfma_f32_16x16x32_f16(
                        af[m], vf, O[m][sd], 0, 0, 0);
            }
        }

        if (more) {
            __syncthreads();                // readers done
            WRITESTAGE();                   // next tile -> LDS
            __syncthreads();                // visible to all
        }
    }
#undef LOADSTAGE
#undef WRITESTAGE

    // ---- rowsum (16-lane DPP), normalize, store ----
    #pragma unroll
    for (int m = 0; m < 2; ++m)
    #pragma unroll
    for (int r = 0; r < 4; ++r) {
        float sum = psum[m][r];
        sum = dpp_addf<0xB1>(sum);
        sum = dpp_addf<0x4E>(sum);
        sum = dpp_addf<0x141>(sum);
        sum = dpp_addf<0x140>(sum);
        const float inv = __builtin_amdgcn_rcpf(sum);
        const int t = t0 + 32 * w + 16 * m + 4 * g4 + r;
        float* op = out + ((t * NH + head) << 6) + c16;
        #pragma unroll
        for (int sd = 0; sd < 4; ++sd)
            op[16 * sd] = O[m][sd][r] * inv;
    }
}

extern "C" void kernel_launch(void* const* d_in, const int* in_sizes, int n_in,
                              void* d_out, int out_size, void* d_ws, size_t ws_size,
                              hipStream_t stream) {
    const float* q   = (const float*)d_in[0];
    const float* k   = (const float*)d_in[1];
    const float* v   = (const float*)d_in[2];
    const int*   cu  = (const int*)d_in[3];
    const int*   ti  = (const int*)d_in[4];
    const float* ts  = (const float*)d_in[5];
    float*       out = (float*)d_out;
    const int num_docs = in_sizes[3] - 1;

    // workspace: exactly 16 MiB (proven envelope from R10-R13)
    uint4* vTp = (uint4*)d_ws;                                        // 8 MiB
    uint4* sH  = (uint4*)((char*)d_ws + (size_t)8 * 1024 * 1024);     // 8 MiB

    hipLaunchKernelGGL(vt_build,  dim3(512),  dim3(256), 0, stream, v, vTp);
    hipLaunchKernelGGL(sel_build, dim3(1024), dim3(256), 0, stream,
                       ti, ts, cu, sH, num_docs);
    // 4 docs x 8 qtiles(128 tok) x 16 heads = 512 blocks, 256 threads
    hipLaunchKernelGGL(dsa_main,  dim3(512),  dim3(256), 0, stream,
                       q, k, vTp, sH, cu, out);
}

// Round 8
// 148.748 us; speedup vs baseline: 1.4394x; 1.4394x over previous
//
#include <hip/hip_runtime.h>
#include <hip/hip_fp16.h>

// DSA varlen sparse attention, MI355X — round 18: spill fix.
// R17 post-mortem: WRITE_SIZE 16.4MB -> 280MB (17x out size) with VGPR=64:
// __launch_bounds__(256,4) capped the allocator and spilled the 8 staging
// uint4 + accumulators to scratch every iteration (~125B/thread/iter = the
// measured 263MB excess). Kernel went HBM-bound on its own spill traffic.
// R18: (1) __launch_bounds__(256) only -- natural ~110 VGPR, no spills;
// 36KB LDS still allows 4 blocks/CU (the TLP R17 wanted); (2) sel prefetch
// issued AFTER the exp phase (needed only at WRITESTAGE two barriers later)
// to cut peak pressure during QK/exp by 16 regs. Math identical to
// R16/R17 (verified absmax 0.015625).
//   sel[t][lr] = scatter-add of selector scores (== reference's clamped-dup
//   handling);  P = exp2(QK^T * 0.125*log2e) .* sel ;  O = P V / rowsum(P).

#define T_TOK 4096
#define NH    16
#define HD    64
#define KSEL  64

typedef _Float16 f16;
typedef _Float16 f16x8 __attribute__((ext_vector_type(8)));
typedef float    f32x4 __attribute__((ext_vector_type(4)));

#define LSTR 72              // LDS row stride in halfs (= 9 uint4, 144B)

static __device__ __forceinline__ float exp2_hw(float x) {
    float r; asm("v_exp_f32 %0, %1" : "=v"(r) : "v"(x)); return r;
}
// DPP adds within 16-lane rows: xor1, xor2, half_mirror, mirror (R10-proven)
template<int CTRL>
static __device__ __forceinline__ float dpp_addf(float x) {
    const int s = __builtin_amdgcn_update_dpp(
        0, __builtin_bit_cast(int, x), CTRL, 0xF, 0xF, true);
    return x + __builtin_bit_cast(float, s);
}
static __device__ __forceinline__ uint4 pack8(float4 a, float4 b) {
    uint4 u;
    u.x = __builtin_bit_cast(unsigned, __floats2half2_rn(a.x, a.y));
    u.y = __builtin_bit_cast(unsigned, __floats2half2_rn(a.z, a.w));
    u.z = __builtin_bit_cast(unsigned, __floats2half2_rn(b.x, b.y));
    u.w = __builtin_bit_cast(unsigned, __floats2half2_rn(b.z, b.w));
    return u;
}

// ---- V -> fp16 TRANSPOSED head-major: vT[h][d][g] (LDS transpose) ----
__global__ __launch_bounds__(256) void vt_build(
    const float* __restrict__ vM, uint4* __restrict__ vT)
{
    __shared__ __align__(16) f16 T[64 * 136];       // [d][128 g], padded
    const int h  = blockIdx.x >> 5;
    const int gb = blockIdx.x & 31;                 // 128-token block
    const int tid = threadIdx.x;
    const int gl = tid >> 1, hf = tid & 1;
    const float* src = vM + (((gb * 128 + gl) * NH + h) << 6) + 32 * hf;
    #pragma unroll
    for (int jj = 0; jj < 8; ++jj) {
        const float4 f = *(const float4*)(src + 4 * jj);
        const int d0 = 32 * hf + 4 * jj;
        T[(d0 + 0) * 136 + gl] = (f16)f.x;
        T[(d0 + 1) * 136 + gl] = (f16)f.y;
        T[(d0 + 2) * 136 + gl] = (f16)f.z;
        T[(d0 + 3) * 136 + gl] = (f16)f.w;
    }
    __syncthreads();
    #pragma unroll
    for (int k = 0; k < 4; ++k) {
        const int idx = tid + 256 * k;              // 1024 u4
        const int d = idx >> 4, c = idx & 15;
        vT[((h * HD + d) << 9) + (gb << 4) + c] = *(const uint4*)&T[d * 136 + 8 * c];
    }
}

// ---- sel[t][lr] scatter-add build: one wave per token ----
__global__ __launch_bounds__(256) void sel_build(
    const int* __restrict__ tidx, const float* __restrict__ tsc,
    const int* __restrict__ cu, uint4* __restrict__ selH, int num_docs)
{
    __shared__ float row[4][1024];
    const int wv = threadIdx.x >> 6, l = threadIdx.x & 63;
    const int t = blockIdx.x * 4 + wv;
    #pragma unroll
    for (int k = 0; k < 4; ++k)
        *(float4*)&row[wv][l * 16 + 4 * k] = make_float4(0.f, 0.f, 0.f, 0.f);
    __syncthreads();
    int seg = 0;
    for (int i = 1; i < num_docs; ++i) if (t >= cu[i]) seg = i;
    const int start = cu[seg];
    const int len   = cu[seg + 1] - start;
    int loc = tidx[t * KSEL + l] - start;
    loc = loc < 0 ? 0 : (loc > len - 1 ? len - 1 : loc);
    atomicAdd(&row[wv][loc], tsc[t * KSEL + l]);
    __syncthreads();
    #pragma unroll
    for (int k = 0; k < 2; ++k) {
        const float* rp = &row[wv][l * 16 + 8 * k];
        const float4 a = *(const float4*)rp;
        const float4 b = *(const float4*)(rp + 4);
        selH[(t << 7) + l * 2 + k] = pack8(a, b);
    }
}

// -------- main: block = (doc, qtile of 128 tok, head); 4 waves --------
__global__ __launch_bounds__(256) void dsa_main(
    const float* __restrict__ qM,
    const float* __restrict__ kM,
    const uint4* __restrict__ vT,
    const uint4* __restrict__ selH,
    const int*   __restrict__ cu,
    float*       __restrict__ out)
{
    __shared__ __align__(16) f16 KtS[64 * LSTR];    //  9 KB [kv][dim]
    __shared__ __align__(16) f16 VtS[64 * LSTR];    //  9 KB [dim][kv]
    __shared__ __align__(16) f16 PS[128 * LSTR];    // 18 KB [tok][kv] sel->P

    const int tid = threadIdx.x;
    const int w   = tid >> 6;          // 0..3
    const int l   = tid & 63;
    const int g4  = l >> 4;
    const int c16 = l & 15;

    const int b    = blockIdx.x;                    // 512 blocks
    const int head = ((b & 7) << 1) | ((b >> 3) & 1);   // head&7 -> XCD pin
    const int doc  = (b >> 4) & 3;
    const int qt   = b >> 6;                        // 0..7

    const int start = cu[doc];
    const int len   = cu[doc + 1] - start;
    const int t0    = start + qt * 128;

    // Q A-fragments in registers, pre-scaled by D^-0.5 * log2(e)
    const float qs = 0.125f * 1.44269504088896f;
    f16x8 qf[2][2];
    #pragma unroll
    for (int m = 0; m < 2; ++m)
    #pragma unroll
    for (int ks = 0; ks < 2; ++ks) {
        const float* qp = qM + (((t0 + 32 * w + 16 * m + c16) * NH + head) << 6)
                        + 32 * ks + 8 * g4;
        float4 a = *(const float4*)qp;
        float4 c = *(const float4*)(qp + 4);
        a.x *= qs; a.y *= qs; a.z *= qs; a.w *= qs;
        c.x *= qs; c.y *= qs; c.z *= qs; c.w *= qs;
        qf[m][ks] = __builtin_bit_cast(f16x8, pack8(a, c));
    }

    f32x4 O[2][4];
    float psum[2][4];
    #pragma unroll
    for (int m = 0; m < 2; ++m)
    #pragma unroll
    for (int sd = 0; sd < 4; ++sd) {
        O[m][sd] = (f32x4){0.f, 0.f, 0.f, 0.f};
        psum[m][sd] = 0.f;
    }

    const int NT = (len + 63) >> 6;
    const int r8 = tid >> 3, c8 = tid & 7;          // r8 0..31

    uint4 kq0, kq1, vq0, vq1, sq0, sq1, sq2, sq3;
#define LOADKV(IT) {                                                         \
        const int grow_ = start + (IT) * 64;                                 \
        const float* kp0_ = kM + (((grow_ + r8     ) * NH + head) << 6) + 8 * c8; \
        const float* kp1_ = kM + (((grow_ + r8 + 32) * NH + head) << 6) + 8 * c8; \
        kq0 = pack8(*(const float4*)kp0_, *(const float4*)(kp0_ + 4));       \
        kq1 = pack8(*(const float4*)kp1_, *(const float4*)(kp1_ + 4));       \
        vq0 = vT[((head * HD + r8     ) << 9) + (grow_ >> 3) + c8];          \
        vq1 = vT[((head * HD + r8 + 32) << 9) + (grow_ >> 3) + c8];          \
    }
#define LOADSEL(IT) {                                                        \
        sq0 = selH[((t0 + r8     ) << 7) + ((IT) << 3) + c8];                \
        sq1 = selH[((t0 + r8 + 32) << 7) + ((IT) << 3) + c8];                \
        sq2 = selH[((t0 + r8 + 64) << 7) + ((IT) << 3) + c8];                \
        sq3 = selH[((t0 + r8 + 96) << 7) + ((IT) << 3) + c8];                \
    }
#define WRITESTAGE() {                                                       \
        ((uint4*)KtS)[(r8     ) * 9 + c8] = kq0;                             \
        ((uint4*)KtS)[(r8 + 32) * 9 + c8] = kq1;                             \
        ((uint4*)VtS)[(r8     ) * 9 + c8] = vq0;                             \
        ((uint4*)VtS)[(r8 + 32) * 9 + c8] = vq1;                             \
        ((uint4*)PS)[(r8     ) * 9 + c8] = sq0;                              \
        ((uint4*)PS)[(r8 + 32) * 9 + c8] = sq1;                              \
        ((uint4*)PS)[(r8 + 64) * 9 + c8] = sq2;                              \
        ((uint4*)PS)[(r8 + 96) * 9 + c8] = sq3;                              \
    }

    LOADKV(0);
    LOADSEL(0);
    WRITESTAGE();
    __syncthreads();

    for (int it = 0; it < NT; ++it) {
        const bool more = (it + 1 < NT);
        if (more) LOADKV(it + 1);           // prefetch next K/V into regs

        // ---- S = Q K^T for this wave's 32 tokens x 64 kv ----
        f32x4 S[2][4];
        #pragma unroll
        for (int m = 0; m < 2; ++m)
        #pragma unroll
        for (int s = 0; s < 4; ++s)
            S[m][s] = (f32x4){0.f, 0.f, 0.f, 0.f};
        #pragma unroll
        for (int ks = 0; ks < 2; ++ks) {
            f16x8 kf[4];
            #pragma unroll
            for (int s = 0; s < 4; ++s)
                kf[s] = __builtin_bit_cast(f16x8,
                    ((const uint4*)KtS)[(16 * s + c16) * 9 + 4 * ks + g4]);
            #pragma unroll
            for (int m = 0; m < 2; ++m)
            #pragma unroll
            for (int s = 0; s < 4; ++s)
                S[m][s] = __builtin_amdgcn_mfma_f32_16x16x32_f16(
                    qf[m][ks], kf[s], S[m][s], 0, 0, 0);
        }

        // ---- P = exp2(min(S,30)) * sel, in place over the sel tile ----
        #pragma unroll
        for (int m = 0; m < 2; ++m)
        #pragma unroll
        for (int s = 0; s < 4; ++s)
        #pragma unroll
        for (int r = 0; r < 4; ++r) {
            const int tok  = 32 * w + 16 * m + 4 * g4 + r;
            const int hidx = tok * LSTR + 16 * s + c16;
            const float sel = (float)PS[hidx];
            const float p = fminf(exp2_hw(fminf(S[m][s][r], 30.f)) * sel,
                                  60000.f);
            psum[m][r] += p;
            PS[hidx] = (f16)p;
        }

        if (more) LOADSEL(it + 1);          // sel needed only at WRITESTAGE

        // fence: f16 stores (above) vs uint4 loads (below) are mixed-TBAA;
        // a real barrier orders them regardless of aliasing assumptions.
        __syncthreads();

        // ---- O += P V  (A = P rows, B = Vt rows) ----
        #pragma unroll
        for (int ks = 0; ks < 2; ++ks) {
            f16x8 af[2];
            #pragma unroll
            for (int m = 0; m < 2; ++m)
                af[m] = __builtin_bit_cast(f16x8,
                    ((const uint4*)PS)[(32 * w + 16 * m + c16) * 9 + 4 * ks + g4]);
            #pragma unroll
            for (int sd = 0; sd < 4; ++sd) {
                const f16x8 vf = __builtin_bit_cast(f16x8,
                    ((const uint4*)VtS)[(16 * sd + c16) * 9 + 4 * ks + g4]);
                #pragma unroll
                for (int m = 0; m < 2; ++m)
                    O[m][sd] = __builtin_amdgcn_mfma_f32_16x16x32_f16(
                        af[m], vf, O[m][sd], 0, 0, 0);
            }
        }

        if (more) {
            __syncthreads();                // readers done
            WRITESTAGE();                   // next tile -> LDS
            __syncthreads();                // visible to all
        }
    }
#undef LOADKV
#undef LOADSEL
#undef WRITESTAGE

    // ---- rowsum (16-lane DPP), normalize, store ----
    #pragma unroll
    for (int m = 0; m < 2; ++m)
    #pragma unroll
    for (int r = 0; r < 4; ++r) {
        float sum = psum[m][r];
        sum = dpp_addf<0xB1>(sum);
        sum = dpp_addf<0x4E>(sum);
        sum = dpp_addf<0x141>(sum);
        sum = dpp_addf<0x140>(sum);
        const float inv = __builtin_amdgcn_rcpf(sum);
        const int t = t0 + 32 * w + 16 * m + 4 * g4 + r;
        float* op = out + ((t * NH + head) << 6) + c16;
        #pragma unroll
        for (int sd = 0; sd < 4; ++sd)
            op[16 * sd] = O[m][sd][r] * inv;
    }
}

extern "C" void kernel_launch(void* const* d_in, const int* in_sizes, int n_in,
                              void* d_out, int out_size, void* d_ws, size_t ws_size,
                              hipStream_t stream) {
    const float* q   = (const float*)d_in[0];
    const float* k   = (const float*)d_in[1];
    const float* v   = (const float*)d_in[2];
    const int*   cu  = (const int*)d_in[3];
    const int*   ti  = (const int*)d_in[4];
    const float* ts  = (const float*)d_in[5];
    float*       out = (float*)d_out;
    const int num_docs = in_sizes[3] - 1;

    // workspace: exactly 16 MiB (proven envelope from R10-R13)
    uint4* vTp = (uint4*)d_ws;                                        // 8 MiB
    uint4* sH  = (uint4*)((char*)d_ws + (size_t)8 * 1024 * 1024);     // 8 MiB

    hipLaunchKernelGGL(vt_build,  dim3(512),  dim3(256), 0, stream, v, vTp);
    hipLaunchKernelGGL(sel_build, dim3(1024), dim3(256), 0, stream,
                       ti, ts, cu, sH, num_docs);
    // 4 docs x 8 qtiles(128 tok) x 16 heads = 512 blocks, 256 threads
    hipLaunchKernelGGL(dsa_main,  dim3(512),  dim3(256), 0, stream,
                       q, k, vTp, sH, cu, out);
}

// Round 9
// 148.258 us; speedup vs baseline: 1.4441x; 1.0033x over previous
//
#include <hip/hip_runtime.h>
#include <hip/hip_fp16.h>

// DSA varlen sparse attention, MI355X — round 19: grid/occupancy reshape.
// R18 post-mortem: spills fixed (WRITE 16.4MB, VGPR=104) but Occupancy
// pinned at 17.7% because the GRID (512 blocks = 2/CU) is the ceiling, not
// resources. R19: wave = 16 tokens (block = 64 tok, 256 thr), grid = 1024
// (4 docs x 16 qtiles x 16 heads) -> 4 blocks/CU, 16 waves/CU. Bonus: the
// exp->PV fence becomes WAVE-LOCAL (each wave's P rows are private), so
// s_waitcnt lgkmcnt(0)+sched_barrier replaces one __syncthreads -> 2 block
// barriers/iter instead of 3. Math identical to R16-R18 (absmax 0.015625):
//   sel[t][lr] = scatter-add of selector scores (== reference's clamped-dup
//   handling);  P = exp2(QK^T * 0.125*log2e) .* sel ;  O = P V / rowsum(P).

#define T_TOK 4096
#define NH    16
#define HD    64
#define KSEL  64

typedef _Float16 f16;
typedef _Float16 f16x8 __attribute__((ext_vector_type(8)));
typedef float    f32x4 __attribute__((ext_vector_type(4)));

#define LSTR 72              // LDS row stride in halfs (= 9 uint4, 144B)

static __device__ __forceinline__ float exp2_hw(float x) {
    float r; asm("v_exp_f32 %0, %1" : "=v"(r) : "v"(x)); return r;
}
// DPP adds within 16-lane rows: xor1, xor2, half_mirror, mirror (R10-proven)
template<int CTRL>
static __device__ __forceinline__ float dpp_addf(float x) {
    const int s = __builtin_amdgcn_update_dpp(
        0, __builtin_bit_cast(int, x), CTRL, 0xF, 0xF, true);
    return x + __builtin_bit_cast(float, s);
}
static __device__ __forceinline__ uint4 pack8(float4 a, float4 b) {
    uint4 u;
    u.x = __builtin_bit_cast(unsigned, __floats2half2_rn(a.x, a.y));
    u.y = __builtin_bit_cast(unsigned, __floats2half2_rn(a.z, a.w));
    u.z = __builtin_bit_cast(unsigned, __floats2half2_rn(b.x, b.y));
    u.w = __builtin_bit_cast(unsigned, __floats2half2_rn(b.z, b.w));
    return u;
}

// ---- V -> fp16 TRANSPOSED head-major: vT[h][d][g] (LDS transpose) ----
__global__ __launch_bounds__(256) void vt_build(
    const float* __restrict__ vM, uint4* __restrict__ vT)
{
    __shared__ __align__(16) f16 T[64 * 136];       // [d][128 g], padded
    const int h  = blockIdx.x >> 5;
    const int gb = blockIdx.x & 31;                 // 128-token block
    const int tid = threadIdx.x;
    const int gl = tid >> 1, hf = tid & 1;
    const float* src = vM + (((gb * 128 + gl) * NH + h) << 6) + 32 * hf;
    #pragma unroll
    for (int jj = 0; jj < 8; ++jj) {
        const float4 f = *(const float4*)(src + 4 * jj);
        const int d0 = 32 * hf + 4 * jj;
        T[(d0 + 0) * 136 + gl] = (f16)f.x;
        T[(d0 + 1) * 136 + gl] = (f16)f.y;
        T[(d0 + 2) * 136 + gl] = (f16)f.z;
        T[(d0 + 3) * 136 + gl] = (f16)f.w;
    }
    __syncthreads();
    #pragma unroll
    for (int k = 0; k < 4; ++k) {
        const int idx = tid + 256 * k;              // 1024 u4
        const int d = idx >> 4, c = idx & 15;
        vT[((h * HD + d) << 9) + (gb << 4) + c] = *(const uint4*)&T[d * 136 + 8 * c];
    }
}

// ---- sel[t][lr] scatter-add build: one wave per token ----
__global__ __launch_bounds__(256) void sel_build(
    const int* __restrict__ tidx, const float* __restrict__ tsc,
    const int* __restrict__ cu, uint4* __restrict__ selH, int num_docs)
{
    __shared__ float row[4][1024];
    const int wv = threadIdx.x >> 6, l = threadIdx.x & 63;
    const int t = blockIdx.x * 4 + wv;
    #pragma unroll
    for (int k = 0; k < 4; ++k)
        *(float4*)&row[wv][l * 16 + 4 * k] = make_float4(0.f, 0.f, 0.f, 0.f);
    __syncthreads();
    int seg = 0;
    for (int i = 1; i < num_docs; ++i) if (t >= cu[i]) seg = i;
    const int start = cu[seg];
    const int len   = cu[seg + 1] - start;
    int loc = tidx[t * KSEL + l] - start;
    loc = loc < 0 ? 0 : (loc > len - 1 ? len - 1 : loc);
    atomicAdd(&row[wv][loc], tsc[t * KSEL + l]);
    __syncthreads();
    #pragma unroll
    for (int k = 0; k < 2; ++k) {
        const float* rp = &row[wv][l * 16 + 8 * k];
        const float4 a = *(const float4*)rp;
        const float4 b = *(const float4*)(rp + 4);
        selH[(t << 7) + l * 2 + k] = pack8(a, b);
    }
}

// -------- main: block = (doc, qtile of 64 tok, head); wave = 16 tokens ------
__global__ __launch_bounds__(256) void dsa_main(
    const float* __restrict__ qM,
    const float* __restrict__ kM,
    const uint4* __restrict__ vT,
    const uint4* __restrict__ selH,
    const int*   __restrict__ cu,
    float*       __restrict__ out)
{
    __shared__ __align__(16) f16 KtS[64 * LSTR];    // 9 KB [kv][dim]
    __shared__ __align__(16) f16 VtS[64 * LSTR];    // 9 KB [dim][kv]
    __shared__ __align__(16) f16 PS[64 * LSTR];     // 9 KB [tok][kv] sel->P

    const int tid = threadIdx.x;
    const int w   = tid >> 6;          // 0..3 (wave = 16 tokens)
    const int l   = tid & 63;
    const int g4  = l >> 4;
    const int c16 = l & 15;

    const int b    = blockIdx.x;                    // 1024 blocks
    const int head = ((b & 7) << 1) | ((b >> 3) & 1);   // head&7 -> XCD pin
    const int doc  = (b >> 4) & 3;
    const int qt   = b >> 6;                        // 0..15

    const int start = cu[doc];
    const int len   = cu[doc + 1] - start;
    const int t0    = start + qt * 64;

    // Q A-fragments in registers, pre-scaled by D^-0.5 * log2(e)
    const float qs = 0.125f * 1.44269504088896f;
    f16x8 qf[2];
    #pragma unroll
    for (int ks = 0; ks < 2; ++ks) {
        const float* qp = qM + (((t0 + 16 * w + c16) * NH + head) << 6)
                        + 32 * ks + 8 * g4;
        float4 a = *(const float4*)qp;
        float4 c = *(const float4*)(qp + 4);
        a.x *= qs; a.y *= qs; a.z *= qs; a.w *= qs;
        c.x *= qs; c.y *= qs; c.z *= qs; c.w *= qs;
        qf[ks] = __builtin_bit_cast(f16x8, pack8(a, c));
    }

    f32x4 O[4];
    float psum[4];
    #pragma unroll
    for (int sd = 0; sd < 4; ++sd) {
        O[sd] = (f32x4){0.f, 0.f, 0.f, 0.f};
        psum[sd] = 0.f;
    }

    const int NT = (len + 63) >> 6;
    const int r8 = tid >> 2, c4 = tid & 3;          // staging: row 0..63, chunk

    uint4 kq0, kq1, vq0, vq1, sq0, sq1;
#define LOADSTAGE(IT) {                                                      \
        const int grow_ = start + (IT) * 64;                                 \
        const float* kp_ = kM + (((grow_ + r8) * NH + head) << 6);           \
        kq0 = pack8(*(const float4*)(kp_ + 8 * c4),                          \
                    *(const float4*)(kp_ + 8 * c4 + 4));                     \
        kq1 = pack8(*(const float4*)(kp_ + 8 * (c4 + 4)),                    \
                    *(const float4*)(kp_ + 8 * (c4 + 4) + 4));               \
        vq0 = vT[((head * HD + r8) << 9) + (grow_ >> 3) + c4];               \
        vq1 = vT[((head * HD + r8) << 9) + (grow_ >> 3) + c4 + 4];           \
        sq0 = selH[((t0 + r8) << 7) + ((IT) << 3) + c4];                     \
        sq1 = selH[((t0 + r8) << 7) + ((IT) << 3) + c4 + 4];                 \
    }
#define WRITESTAGE() {                                                       \
        ((uint4*)KtS)[r8 * 9 + c4    ] = kq0;                                \
        ((uint4*)KtS)[r8 * 9 + c4 + 4] = kq1;                                \
        ((uint4*)VtS)[r8 * 9 + c4    ] = vq0;                                \
        ((uint4*)VtS)[r8 * 9 + c4 + 4] = vq1;                                \
        ((uint4*)PS )[r8 * 9 + c4    ] = sq0;                                \
        ((uint4*)PS )[r8 * 9 + c4 + 4] = sq1;                                \
    }

    LOADSTAGE(0);
    WRITESTAGE();
    __syncthreads();

    for (int it = 0; it < NT; ++it) {
        const bool more = (it + 1 < NT);
        if (more) LOADSTAGE(it + 1);        // prefetch next tile into regs

        // ---- S = Q K^T for this wave's 16 tokens x 64 kv ----
        f32x4 S[4];
        #pragma unroll
        for (int s = 0; s < 4; ++s) S[s] = (f32x4){0.f, 0.f, 0.f, 0.f};
        #pragma unroll
        for (int ks = 0; ks < 2; ++ks) {
            #pragma unroll
            for (int s = 0; s < 4; ++s) {
                const f16x8 kf = __builtin_bit_cast(f16x8,
                    ((const uint4*)KtS)[(16 * s + c16) * 9 + 4 * ks + g4]);
                S[s] = __builtin_amdgcn_mfma_f32_16x16x32_f16(
                    qf[ks], kf, S[s], 0, 0, 0);
            }
        }

        // ---- P = exp2(min(S,30)) * sel, in place over the sel tile ----
        // PS rows [16w,16w+16) are THIS WAVE's private rows.
        #pragma unroll
        for (int s = 0; s < 4; ++s)
        #pragma unroll
        for (int r = 0; r < 4; ++r) {
            const int tok  = 16 * w + 4 * g4 + r;
            const int hidx = tok * LSTR + 16 * s + c16;
            const float sel = (float)PS[hidx];
            const float p = fminf(exp2_hw(fminf(S[s][r], 30.f)) * sel,
                                  60000.f);
            psum[r] += p;
            PS[hidx] = (f16)p;
        }

        // wave-local fence: P writes (f16) -> af reads (uint4) are same-wave
        // only; order them without a block barrier. (rule #18: sched_barrier
        // right after the counted wait.)
        asm volatile("s_waitcnt lgkmcnt(0)" ::: "memory");
        __builtin_amdgcn_sched_barrier(0);

        // ---- O += P V  (A = P rows, B = Vt rows) ----
        #pragma unroll
        for (int ks = 0; ks < 2; ++ks) {
            const f16x8 af = __builtin_bit_cast(f16x8,
                ((const uint4*)PS)[(16 * w + c16) * 9 + 4 * ks + g4]);
            #pragma unroll
            for (int sd = 0; sd < 4; ++sd) {
                const f16x8 vf = __builtin_bit_cast(f16x8,
                    ((const uint4*)VtS)[(16 * sd + c16) * 9 + 4 * ks + g4]);
                O[sd] = __builtin_amdgcn_mfma_f32_16x16x32_f16(
                    af, vf, O[sd], 0, 0, 0);
            }
        }

        if (more) {
            __syncthreads();                // all waves done reading tiles
            WRITESTAGE();                   // next tile -> LDS
            __syncthreads();                // visible to all
        }
    }
#undef LOADSTAGE
#undef WRITESTAGE

    // ---- rowsum (16-lane DPP), normalize, store ----
    #pragma unroll
    for (int r = 0; r < 4; ++r) {
        float sum = psum[r];
        sum = dpp_addf<0xB1>(sum);
        sum = dpp_addf<0x4E>(sum);
        sum = dpp_addf<0x141>(sum);
        sum = dpp_addf<0x140>(sum);
        const float inv = __builtin_amdgcn_rcpf(sum);
        const int t = t0 + 16 * w + 4 * g4 + r;
        float* op = out + ((t * NH + head) << 6) + c16;
        #pragma unroll
        for (int sd = 0; sd < 4; ++sd)
            op[16 * sd] = O[sd][r] * inv;
    }
}

extern "C" void kernel_launch(void* const* d_in, const int* in_sizes, int n_in,
                              void* d_out, int out_size, void* d_ws, size_t ws_size,
                              hipStream_t stream) {
    const float* q   = (const float*)d_in[0];
    const float* k   = (const float*)d_in[1];
    const float* v   = (const float*)d_in[2];
    const int*   cu  = (const int*)d_in[3];
    const int*   ti  = (const int*)d_in[4];
    const float* ts  = (const float*)d_in[5];
    float*       out = (float*)d_out;
    const int num_docs = in_sizes[3] - 1;

    // workspace: exactly 16 MiB (proven envelope from R10-R13)
    uint4* vTp = (uint4*)d_ws;                                        // 8 MiB
    uint4* sH  = (uint4*)((char*)d_ws + (size_t)8 * 1024 * 1024);     // 8 MiB

    hipLaunchKernelGGL(vt_build,  dim3(512),  dim3(256), 0, stream, v, vTp);
    hipLaunchKernelGGL(sel_build, dim3(1024), dim3(256), 0, stream,
                       ti, ts, cu, sH, num_docs);
    // 4 docs x 16 qtiles(64 tok) x 16 heads = 1024 blocks, 256 threads
    hipLaunchKernelGGL(dsa_main,  dim3(1024), dim3(256), 0, stream,
                       q, k, vTp, sH, cu, out);
}